// Round 3
// baseline (176.740 us; speedup 1.0000x reference)
//
#include <hip/hip_runtime.h>

typedef __attribute__((ext_vector_type(8))) short short8;
typedef __attribute__((ext_vector_type(4))) float f32x4;

__device__ __forceinline__ float sigmoidf_(float x) { return 1.f / (1.f + __expf(-x)); }
__device__ __forceinline__ unsigned bf16rne(float x) {
    unsigned b = __float_as_uint(x);
    return (b + 0x7FFFu + ((b >> 16) & 1u)) >> 16;
}

// ws layout (float words):
//   OFFM:  lvl0 @0 (2359296), lvl1 @2359296 (589824), lvl2 @2949120 (147456)
//   MOD:   lvl0 @3096576 (1179648), lvl1 @4276224 (294912), lvl2 @4571136 (73728)
//   MEAN:  lvl0 @4644864 (65536), lvl1 @4710400 (16384), lvl2 @4726784 (4096)
//   WREP:  @4730880, 3*62784 floats; per lvl as u32:
//          [0..18432)     WB   dgemm B-frags
//          [36864..41984) WBO2 offset-conv B-frags, split-half K
//          [41984..55808) WBM  mod-conv B-frags
//   XTb:   @4919232 as u32 (bf16 pairs, 8 u32/px): lvl0 +0, lvl1 +1048576, lvl2 +1310720
// R18: (a) k1 staging = two 32-load register bursts (8->2 serial HBM latencies per
// phase, LDS stays 28.5KB); (b) k1 offset B-frags hoisted above g-loop (10 loads not
// 40); (c) k2 gemm blocks XCD-coupled to their k1 producer (d%8 == t1%8, bijective
// permutation: 168/class) so OFFM/MOD reads hit the producer XCD's L2.

struct P {
    const float *sou0, *sou1, *sou2;
    const float *ref0, *ref1, *ref2;
    const float *ob0, *ob1, *ob2;
    const float *mb0, *mb1, *mb2;
    float* out;
    float* ws;
};

union U {
    uint4 u4; int4 i4; short8 s8; f32x4 f4;
};

// ---------------- K0: fused weight repack (all levels) --------------------------------
__global__ __launch_bounds__(256) void repack_all(
    const float* __restrict__ ow0, const float* __restrict__ mw0, const float* __restrict__ rw0,
    const float* __restrict__ ow1, const float* __restrict__ mw1, const float* __restrict__ rw1,
    const float* __restrict__ ow2, const float* __restrict__ mw2, const float* __restrict__ rw2,
    float* __restrict__ dst) {
    const int lvl = blockIdx.y;
    const float* ow = lvl == 0 ? ow0 : (lvl == 1 ? ow1 : ow2);
    const float* mw = lvl == 0 ? mw0 : (lvl == 1 ? mw1 : mw2);
    const float* rw = lvl == 0 ? rw0 : (lvl == 1 ? rw1 : rw2);
    unsigned* d = (unsigned*)(dst + lvl * 62784);
    int i = blockIdx.x * 256 + threadIdx.x;
    if (i < 18432) {  // WB (dgemm): ((wvu*18+ks)*64+lane)*4+jw
        int jw = i & 3;
        int lane = (i >> 2) & 63;
        int t3 = i >> 8;
        int ks = t3 % 18, wvu = t3 / 18;
        int o = wvu * 16 + (lane & 15);
        int c0 = ks * 32 + (lane >> 4) * 8 + 2 * jw;
        int g0 = c0 / 144, r0 = c0 % 144;
        int c1 = c0 + 1;
        int g1 = c1 / 144, r1 = c1 % 144;
        float w0 = rw[o * 576 + (g0 * 16 + (r0 & 15)) * 9 + (r0 >> 4)];
        float w1 = rw[o * 576 + (g1 * 16 + (r1 & 15)) * 9 + (r1 >> 4)];
        d[i] = bf16rne(w0) | (bf16rne(w1) << 16);
    } else if (i < 23552) {  // WBO2: split-half offset B-frags (5120 u32)
        int o2 = i - 18432;
        int jw = o2 & 3;
        int lane = (o2 >> 2) & 63;
        int t2 = o2 >> 8;          // 0..19 = (h*5+ks)*2+nt
        int nt = t2 & 1;
        int hk = t2 >> 1;          // 0..9
        int ks = hk % 5, h = hk / 5;
        int n = nt * 16 + (lane & 15);
        int K = ks * 32 + (lane >> 4) * 8 + 2 * jw;
        int tap = K >> 4, ch = K & 15;
        bool ok = (n < 18) && (tap < 9);
        float w0 = ok ? ow[n * 288 + (h * 16 + ch) * 9 + tap] : 0.f;
        float w1 = ok ? ow[n * 288 + (h * 16 + ch + 1) * 9 + tap] : 0.f;
        d[36864 + o2] = bf16rne(w0) | (bf16rne(w1) << 16);
    } else if (i < 37376) {  // WBM (13824 u32) at 41984
        int o3 = i - 23552;
        int jw = o3 & 3;
        int lane = (o3 >> 2) & 63;
        int t3 = o3 >> 8;           // 0..53
        int nt = t3 % 3, tc = t3 / 3;
        int tap = tc >> 1, c = tc & 1;
        int n = nt * 16 + (lane & 15);
        int ic0 = c * 32 + (lane >> 4) * 8 + 2 * jw;
        float w0 = (n < 36) ? mw[n * 576 + ic0 * 9 + tap] : 0.f;
        float w1 = (n < 36) ? mw[n * 576 + (ic0 + 1) * 9 + tap] : 0.f;
        d[41984 + o3] = bf16rne(w0) | (bf16rne(w1) << 16);
    }
}

// ---------------- K1: fused mod+offset conv + XTb + MEAN (672 blocks) -----------------
__global__ __launch_bounds__(256) void k1_prep(P p) {
    __shared__ __align__(16) char smem[28512];  // 198 rows x 72 shorts
    const int t = blockIdx.x;
    float* ws = p.ws;
    const int tid = threadIdx.x;

    int lvl, j;
    if (t < 512) { lvl = 0; j = t; }
    else if (t < 640) { lvl = 1; j = t - 512; }
    else { lvl = 2; j = t - 640; }
    const int logW = 7 - lvl;
    const int W = 1 << logW, H = W, HW = H * W;
    const int nper = 256 >> (2 * lvl);
    const int qb = j % nper, b = j / nper;
    const int q0 = qb * 64;
    const int hlo = q0 >> logW;
    const int xlo = q0 & (W - 1);
    const int cols = (W >= 64) ? 66 : 34;
    const int rcTot = (W >= 64) ? 198 : 136;
    const float* sou = lvl == 0 ? p.sou0 : (lvl == 1 ? p.sou1 : p.sou2);
    const float* ref = lvl == 0 ? p.ref0 : (lvl == 1 ? p.ref1 : p.ref2);
    const float* base_s = sou + (size_t)b * 64 * HW;
    const float* base_r = ref + (size_t)b * 64 * HW;
    unsigned* ldsW = (unsigned*)smem;  // row stride 36 dw (72 shorts)
    const bool sact = tid < rcTot;
    const int srow = tid / cols, scol = tid - srow * cols;
    const int grow = hlo - 1 + srow, gcol = xlo - 1 + scol;
    const bool inb = sact && grow >= 0 && grow < H && gcol >= 0 && gcol < W;
    const size_t goff = inb ? ((size_t)grow * W + gcol) : 0;

    float v[32];
    // ---- stage sou: two 32-load bursts (all loads issued before first conversion) ----
#pragma unroll
    for (int hb = 0; hb < 2; ++hb) {
#pragma unroll
        for (int c8 = 0; c8 < 4; ++c8) {
            const float* p0 = base_s + (size_t)((hb * 4 + c8) * 8) * HW;
#pragma unroll
            for (int jj = 0; jj < 8; ++jj)
                v[c8 * 8 + jj] = inb ? p0[(size_t)jj * HW + goff] : 0.f;
        }
        if (sact) {
#pragma unroll
            for (int c8 = 0; c8 < 4; ++c8) {
                uint4 wv;
                wv.x = bf16rne(v[c8 * 8 + 0]) | (bf16rne(v[c8 * 8 + 1]) << 16);
                wv.y = bf16rne(v[c8 * 8 + 2]) | (bf16rne(v[c8 * 8 + 3]) << 16);
                wv.z = bf16rne(v[c8 * 8 + 4]) | (bf16rne(v[c8 * 8 + 5]) << 16);
                wv.w = bf16rne(v[c8 * 8 + 6]) | (bf16rne(v[c8 * 8 + 7]) << 16);
                *(uint4*)&ldsW[tid * 36 + (hb * 4 + c8) * 4] = wv;
            }
        }
    }
    __syncthreads();

    // ---- emit XTb for the central 64 px straight from the staged sou tile -----------
    unsigned* XTb = (unsigned*)(ws + 4919232) +
                    (lvl == 0 ? 0 : (lvl == 1 ? 1048576 : 1310720));
#pragma unroll
    for (int u = 0; u < 2; ++u) {
        const int idx = tid * 2 + u;       // 0..511
        const int px = idx >> 3, gh = idx & 7;
        const int g = gh >> 1, half = gh & 1;
        const int rc = ((px >> logW) + 1) * cols + (px & (W - 1)) + 1;
        uint4 vv = *(const uint4*)&ldsW[rc * 36 + g * 8 + half * 4];
        *(uint4*)(XTb + ((size_t)(b * 4 + g) * HW + q0 + px) * 8 + half * 4) = vv;
    }

    // ---- MFMA phase on sou tile: mod conv + offset half0 ----------------------------
    const int wvu = __builtin_amdgcn_readfirstlane(tid >> 6);
    const int lane = tid & 63, quad = lane >> 4, lo16 = lane & 15;
    const int qg = q0 + wvu * 16 + lo16;
    const int rowB = (qg >> logW) - hlo;
    const int colB = (qg & (W - 1)) - xlo;
    const unsigned short* ldsS = (const unsigned short*)smem;
    const unsigned* WREPu = (const unsigned*)(ws + 4730880 + lvl * 62784);
    const unsigned* WBO2 = WREPu + 36864;
    const unsigned* WBM = WREPu + 41984;

    f32x4 accM[3], accO[4][2];
#pragma unroll
    for (int nt = 0; nt < 3; ++nt) accM[nt] = (f32x4){0.f, 0.f, 0.f, 0.f};
#pragma unroll
    for (int g = 0; g < 4; ++g)
#pragma unroll
        for (int nt = 0; nt < 2; ++nt) accO[g][nt] = (f32x4){0.f, 0.f, 0.f, 0.f};

    // mod conv: 9 taps x 2 chunks x 3 ntiles
#pragma unroll
    for (int tap = 0; tap < 9; ++tap) {
        const int ky = tap / 3, kx = tap - ky * 3;
        const int rc = (rowB + ky) * cols + colB + kx;
#pragma unroll
        for (int c = 0; c < 2; ++c) {
            U au; au.s8 = *(const short8*)&ldsS[rc * 72 + c * 32 + quad * 8];
#pragma unroll
            for (int nt = 0; nt < 3; ++nt) {
                U bu;
                bu.u4 = *(const uint4*)(WBM + (((tap * 2 + c) * 3 + nt) * 64 + lane) * 4);
                accM[nt] = __builtin_amdgcn_mfma_f32_16x16x32_bf16(au.s8, bu.s8, accM[nt], 0, 0, 0);
            }
        }
    }
    // offset half0 (sou): B-frags hoisted above g loop (2 loads per ks, not 8)
#pragma unroll
    for (int ks = 0; ks < 5; ++ks) {
        const int Kbase = ks * 32 + quad * 8;
        const int tap = min(Kbase >> 4, 8);
        const int ky = tap / 3, kx = tap - ky * 3;
        const int rc = (rowB + ky) * cols + colB + kx;
        const int choff = Kbase & 15;  // 0 or 8
        U bu0, bu1;
        bu0.u4 = *(const uint4*)(WBO2 + ((ks * 2 + 0) * 64 + lane) * 4);
        bu1.u4 = *(const uint4*)(WBO2 + ((ks * 2 + 1) * 64 + lane) * 4);
#pragma unroll
        for (int g = 0; g < 4; ++g) {
            U au; au.s8 = *(const short8*)&ldsS[rc * 72 + g * 16 + choff];
            accO[g][0] = __builtin_amdgcn_mfma_f32_16x16x32_bf16(au.s8, bu0.s8, accO[g][0], 0, 0, 0);
            accO[g][1] = __builtin_amdgcn_mfma_f32_16x16x32_bf16(au.s8, bu1.s8, accO[g][1], 0, 0, 0);
        }
    }
    __syncthreads();

    // ---- re-stage ref (64 ch) in place, same two-burst pattern -----------------------
#pragma unroll
    for (int hb = 0; hb < 2; ++hb) {
#pragma unroll
        for (int c8 = 0; c8 < 4; ++c8) {
            const float* p0 = base_r + (size_t)((hb * 4 + c8) * 8) * HW;
#pragma unroll
            for (int jj = 0; jj < 8; ++jj)
                v[c8 * 8 + jj] = inb ? p0[(size_t)jj * HW + goff] : 0.f;
        }
        if (sact) {
#pragma unroll
            for (int c8 = 0; c8 < 4; ++c8) {
                uint4 wv;
                wv.x = bf16rne(v[c8 * 8 + 0]) | (bf16rne(v[c8 * 8 + 1]) << 16);
                wv.y = bf16rne(v[c8 * 8 + 2]) | (bf16rne(v[c8 * 8 + 3]) << 16);
                wv.z = bf16rne(v[c8 * 8 + 4]) | (bf16rne(v[c8 * 8 + 5]) << 16);
                wv.w = bf16rne(v[c8 * 8 + 6]) | (bf16rne(v[c8 * 8 + 7]) << 16);
                *(uint4*)&ldsW[tid * 36 + (hb * 4 + c8) * 4] = wv;
            }
        }
        if (hb == 0) __syncthreads();  // ensure half-written rows not read early?  No:
        // NOTE: reads of the ref tile happen only after the barrier below; the mid-burst
        // barrier is unnecessary for correctness but keeps both bursts' LDS writes
        // ordered cheaply.  Removed: see barrier below.
    }
    __syncthreads();

    // ---- offset half1 (ref) ----------------------------------------------------------
#pragma unroll
    for (int ks = 0; ks < 5; ++ks) {
        const int Kbase = ks * 32 + quad * 8;
        const int tap = min(Kbase >> 4, 8);
        const int ky = tap / 3, kx = tap - ky * 3;
        const int rc = (rowB + ky) * cols + colB + kx;
        const int choff = Kbase & 15;
        U bu0, bu1;
        bu0.u4 = *(const uint4*)(WBO2 + (((5 + ks) * 2 + 0) * 64 + lane) * 4);
        bu1.u4 = *(const uint4*)(WBO2 + (((5 + ks) * 2 + 1) * 64 + lane) * 4);
#pragma unroll
        for (int g = 0; g < 4; ++g) {
            U au; au.s8 = *(const short8*)&ldsS[rc * 72 + g * 16 + choff];
            accO[g][0] = __builtin_amdgcn_mfma_f32_16x16x32_bf16(au.s8, bu0.s8, accO[g][0], 0, 0, 0);
            accO[g][1] = __builtin_amdgcn_mfma_f32_16x16x32_bf16(au.s8, bu1.s8, accO[g][1], 0, 0, 0);
        }
    }

    // ---- epilogues ------------------------------------------------------------------
    {
        const float* bias = lvl == 0 ? p.mb0 : (lvl == 1 ? p.mb1 : p.mb2);
        float* MOD = ws + (lvl == 0 ? 3096576 : (lvl == 1 ? 4276224 : 4571136));
#pragma unroll
        for (int nt = 0; nt < 3; ++nt) {
            const int o = nt * 16 + lo16;
            if (o < 36) {
                const float bb = bias[o];
                float* op = MOD + (size_t)(b * 36 + o) * HW + q0 + wvu * 16 + quad * 4;
                *(float4*)op = make_float4(2.f * sigmoidf_(accM[nt][0] + bb),
                                           2.f * sigmoidf_(accM[nt][1] + bb),
                                           2.f * sigmoidf_(accM[nt][2] + bb),
                                           2.f * sigmoidf_(accM[nt][3] + bb));
            }
        }
    }
    {
        const float* bias = lvl == 0 ? p.ob0 : (lvl == 1 ? p.ob1 : p.ob2);
        float* OFFM = ws + (lvl == 0 ? 0 : (lvl == 1 ? 2359296 : 2949120));
        const float rng = 0.25f * (float)H;
        float macc[4] = {0.f, 0.f, 0.f, 0.f};  // per-lane partial of dy or dx sums
#pragma unroll
        for (int g = 0; g < 4; ++g)
#pragma unroll
            for (int nt = 0; nt < 2; ++nt) {
                const int o = nt * 16 + lo16;
                if (o < 18) {
                    const float bb = bias[o];
                    float ovv[4];
#pragma unroll
                    for (int rg = 0; rg < 4; ++rg)
                        ovv[rg] = rng * (2.f * sigmoidf_(accO[g][nt][rg] + bb) - 1.f);
                    float* op = OFFM + (size_t)(b * 72 + g * 18 + o) * HW + q0 + wvu * 16 + quad * 4;
                    *(float4*)op = make_float4(ovv[0], ovv[1], ovv[2], ovv[3]);
#pragma unroll
                    for (int rg = 0; rg < 4; ++rg) macc[rg] += ovv[rg];
                }
            }
        // o parity == lo16 parity: even lanes hold dy partials, odd lanes dx partials.
        const bool odd = (lo16 & 1) != 0;
        float my[4], mx[4];
#pragma unroll
        for (int rg = 0; rg < 4; ++rg) {
            my[rg] = odd ? 0.f : macc[rg];
            mx[rg] = odd ? macc[rg] : 0.f;
        }
#pragma unroll
        for (int m = 1; m < 16; m <<= 1) {
#pragma unroll
            for (int rg = 0; rg < 4; ++rg) {
                my[rg] += __shfl_xor(my[rg], m);
                mx[rg] += __shfl_xor(mx[rg], m);
            }
        }
        if (lo16 == 0) {
            float* MEAN = ws + (lvl == 0 ? 4644864 : (lvl == 1 ? 4710400 : 4726784));
            const int pxb = q0 + wvu * 16 + quad * 4;
            const float inv = 1.f / 36.f;
            *(float4*)(MEAN + (size_t)(b * 2) * HW + pxb) =
                make_float4(my[0] * inv, my[1] * inv, my[2] * inv, my[3] * inv);
            *(float4*)(MEAN + (size_t)(b * 2 + 1) * HW + pxb) =
                make_float4(mx[0] * inv, mx[1] * inv, mx[2] * inv, mx[3] * inv);
        }
    }
}

// ---------------- K2: FUSED gather+dgemm(1344) + upsample(3072) -----------------------
__global__ __launch_bounds__(256) void k2_fused(P p) {
    __shared__ __align__(16) unsigned lds[32 * 100];  // px-major, stride 100 dw (12.8 KB)
    const int t = blockIdx.x;
    float* ws = p.ws;
    const int tid = threadIdx.x;
    if (t < 1344) {
        // XCD-coupled decode: dispatch index t with t%8 == producer k1 block %8.
        // Per class x: 128 lvl0 + 32 lvl1 + 8 lvl2 = 168 = 1344/8 (bijective).
        const int x = t & 7, r = t >> 3;
        int lvl, u;
        if (r < 128) { lvl = 0; u = x + ((r >> 1) << 3); }
        else if (r < 160) { lvl = 1; u = x + (((r - 128) >> 1) << 3); }
        else { lvl = 2; u = x + (((r - 160) >> 1) << 3); }
        const int j = 2 * u + (r & 1);
        const int logW = 7 - lvl;
        const int W = 1 << logW, H = W, HW = H * W;
        const int nper = 512 >> (2 * lvl);
        const int qb = j % nper, b = j / nper;
        const int q0 = qb * 32;
        const float* OFFM = ws + (lvl == 0 ? 0 : (lvl == 1 ? 2359296 : 2949120));
        const float* MOD = ws + (lvl == 0 ? 3096576 : (lvl == 1 ? 4276224 : 4571136));
        const unsigned* XTb = (const unsigned*)(ws + 4919232) +
                              (lvl == 0 ? 0 : (lvl == 1 ? 1048576 : 1310720));
        const unsigned* WB = (const unsigned*)(ws + 4730880 + lvl * 62784);
        float* outp = p.out + (lvl == 0 ? 655360 : (lvl == 1 ? 131072 : 0));
        const int wvu = __builtin_amdgcn_readfirstlane(tid >> 6);
        const int lane = tid & 63, quad = lane >> 4, lo16 = lane & 15;
        f32x4 acc[2];
        acc[0] = (f32x4){0.f, 0.f, 0.f, 0.f};
        acc[1] = (f32x4){0.f, 0.f, 0.f, 0.f};
        for (int c = 0; c < 3; ++c) {
            if (c) __syncthreads();
#pragma unroll
            for (int it = 0; it < 2; ++it) {
                const int task = it * 256 + tid;
                if (task < 384) {
                    const int gkl = task >> 5, px = task & 31;
                    const int gk = c * 12 + gkl;
                    const int g = gk / 9, k = gk - g * 9;
                    const int q = q0 + px;
                    const int h = q >> logW, xp = q & (W - 1);
                    const int ky = k / 3, kx = k - ky * 3;
                    float dy = OFFM[(size_t)(b * 72 + g * 18 + 2 * k) * HW + q];
                    float dx = OFFM[(size_t)(b * 72 + g * 18 + 2 * k + 1) * HW + q];
                    float m = MOD[(size_t)(b * 36 + g * 9 + k) * HW + q];
                    float py = (float)(h - 1 + ky) + dy;
                    float pxx = (float)(xp - 1 + kx) + dx;
                    float y0f = floorf(py), x0f = floorf(pxx);
                    float wy = py - y0f, wx = pxx - x0f;
                    int y0 = (int)y0f, x0 = (int)x0f;
                    const unsigned* xg = XTb + (size_t)(b * 4 + g) * HW * 8;
                    float s[16];
#pragma unroll
                    for (int cc = 0; cc < 16; ++cc) s[cc] = 0.f;
#pragma unroll
                    for (int cor = 0; cor < 4; ++cor) {
                        int yy = y0 + (cor >> 1), xx = x0 + (cor & 1);
                        float cw = ((cor >> 1) ? wy : 1.f - wy) * ((cor & 1) ? wx : 1.f - wx);
                        cw = (yy >= 0 && yy < H && xx >= 0 && xx < W) ? cw * m : 0.f;
                        int yc = min(max(yy, 0), H - 1), xc = min(max(xx, 0), W - 1);
                        const uint4* cp = (const uint4*)(xg + (size_t)((yc << logW) + xc) * 8);
                        unsigned cbuf[8];
                        *(uint4*)&cbuf[0] = cp[0];
                        *(uint4*)&cbuf[4] = cp[1];
#pragma unroll
                        for (int pr = 0; pr < 8; ++pr) {
                            float lo = __uint_as_float(cbuf[pr] << 16);
                            float hi = __uint_as_float(cbuf[pr] & 0xFFFF0000u);
                            s[2 * pr] = fmaf(cw, lo, s[2 * pr]);
                            s[2 * pr + 1] = fmaf(cw, hi, s[2 * pr + 1]);
                        }
                    }
                    // px-major store: rows gkl*8..gkl*8+7 as two b128 writes
                    unsigned* dp = &lds[px * 100 + gkl * 8];
                    uint4 w0, w1;
                    w0.x = bf16rne(s[0]) | (bf16rne(s[1]) << 16);
                    w0.y = bf16rne(s[2]) | (bf16rne(s[3]) << 16);
                    w0.z = bf16rne(s[4]) | (bf16rne(s[5]) << 16);
                    w0.w = bf16rne(s[6]) | (bf16rne(s[7]) << 16);
                    w1.x = bf16rne(s[8]) | (bf16rne(s[9]) << 16);
                    w1.y = bf16rne(s[10]) | (bf16rne(s[11]) << 16);
                    w1.z = bf16rne(s[12]) | (bf16rne(s[13]) << 16);
                    w1.w = bf16rne(s[14]) | (bf16rne(s[15]) << 16);
                    *(uint4*)dp = w0;
                    *(uint4*)(dp + 4) = w1;
                }
            }
            __syncthreads();
            uint4 bfr[6];
#pragma unroll
            for (int k6 = 0; k6 < 6; ++k6)
                bfr[k6] = *(const uint4*)(WB + (((wvu * 18 + c * 6 + k6) * 64 + lane) << 2));
#pragma unroll
            for (int k6 = 0; k6 < 6; ++k6) {
                U bu; bu.u4 = bfr[k6];
#pragma unroll
                for (int mt = 0; mt < 2; ++mt) {
                    const int px = mt * 16 + lo16;
                    U au;
                    au.u4 = *(const uint4*)&lds[px * 100 + k6 * 16 + quad * 4];
                    acc[mt] = __builtin_amdgcn_mfma_f32_16x16x32_bf16(au.s8, bu.s8, acc[mt], 0, 0, 0);
                }
            }
        }
        float* op = outp + (size_t)(b * 64 + wvu * 16 + lo16) * HW + q0;
#pragma unroll
        for (int mt = 0; mt < 2; ++mt)
#pragma unroll
            for (int rg = 0; rg < 4; ++rg)
                op[mt * 16 + quad * 4 + rg] = acc[mt][rg];
    } else {
        // ---- upsample (formerly K3): MEAN written by k1, independent of gemm blocks --
        int flat = ((t - 1344) * 256 + tid) * 4;
        int lvl = flat >> 20;
        int r = flat & 1048575;
        int b = r >> 19, c = (r >> 18) & 1;
        int pix = r & 262143;
        int yo = pix >> 9, xo = pix & 511;
        const int H = 128 >> lvl, W = H;
        const float* MEAN = ws + (lvl == 0 ? 4644864 : (lvl == 1 ? 4710400 : 4726784));
        const float* m = MEAN + (size_t)(b * 2 + c) * H * W;
        float* o = p.out + (lvl == 0 ? 4849664 : (lvl == 1 ? 3801088 : 2752512)) +
                   ((size_t)(b * 2 + c) * 512 + yo) * 512 + xo;
        const float fs = (float)(4 << lvl);
        const float sc = (float)(H - 1) * (1.f / 511.f);
        float sy = yo * sc;
        int y0 = min((int)sy, H - 2);
        float wy = sy - (float)y0;
        float rr[4];
#pragma unroll
        for (int u = 0; u < 4; ++u) {
            float sx = (float)(xo + u) * sc;
            int x0 = min((int)sx, W - 2);
            float wx = sx - (float)x0;
            float v00 = m[y0 * W + x0], v01 = m[y0 * W + x0 + 1];
            float v10 = m[(y0 + 1) * W + x0], v11 = m[(y0 + 1) * W + x0 + 1];
            float r0 = v00 * (1.f - wy) + v10 * wy;
            float r1 = v01 * (1.f - wy) + v11 * wy;
            rr[u] = (r0 * (1.f - wx) + r1 * wx) * fs;
        }
        *(float4*)o = make_float4(rr[0], rr[1], rr[2], rr[3]);
    }
}

extern "C" void kernel_launch(void* const* d_in, const int* in_sizes, int n_in,
                              void* d_out, int out_size, void* d_ws, size_t ws_size,
                              hipStream_t stream) {
    const float* fin[21];
    for (int i = 0; i < 21; ++i) fin[i] = (const float*)d_in[i];
    P p;
    if (in_sizes[1] == in_sizes[0]) {  // dict order sou1,ref1,sou2,ref2,sou3,ref3
        p.sou0 = fin[0]; p.ref0 = fin[1];
        p.sou1 = fin[2]; p.ref1 = fin[3];
        p.sou2 = fin[4]; p.ref2 = fin[5];
    } else {  // arg order
        p.sou0 = fin[0]; p.sou1 = fin[1]; p.sou2 = fin[2];
        p.ref0 = fin[3]; p.ref1 = fin[4]; p.ref2 = fin[5];
    }
    p.ob0 = fin[7]; p.mb0 = fin[9];
    p.ob1 = fin[12]; p.mb1 = fin[14];
    p.ob2 = fin[17]; p.mb2 = fin[19];
    p.out = (float*)d_out;
    p.ws = (float*)d_ws;

    repack_all<<<dim3(146, 3), 256, 0, stream>>>(
        fin[6], fin[8], fin[10], fin[11], fin[13], fin[15], fin[16], fin[18], fin[20],
        p.ws + 4730880);
    k1_prep<<<dim3(672), 256, 0, stream>>>(p);
    k2_fused<<<dim3(4416), 256, 0, stream>>>(p);
}

// Round 4
// 170.028 us; speedup vs baseline: 1.0395x; 1.0395x over previous
//
#include <hip/hip_runtime.h>

typedef __attribute__((ext_vector_type(8))) short short8;
typedef __attribute__((ext_vector_type(4))) float f32x4;

__device__ __forceinline__ float sigmoidf_(float x) { return 1.f / (1.f + __expf(-x)); }
__device__ __forceinline__ unsigned bf16rne(float x) {
    unsigned b = __float_as_uint(x);
    return (b + 0x7FFFu + ((b >> 16) & 1u)) >> 16;
}

// ws layout (float words):
//   OFFM:  lvl0 @0 (2359296), lvl1 @2359296 (589824), lvl2 @2949120 (147456)
//   MOD:   lvl0 @3096576 (1179648), lvl1 @4276224 (294912), lvl2 @4571136 (73728)
//   MEAN:  lvl0 @4644864 (65536), lvl1 @4710400 (16384), lvl2 @4726784 (4096)
//   WREP:  @4730880, 3*62784 floats; per lvl as u32:
//          [0..18432)     WB   dgemm B-frags
//          [36864..41984) WBO2 offset-conv B-frags, split-half K
//          [41984..55808) WBM  mod-conv B-frags
//   XTb:   @4919232 as u32 (bf16 pairs, 8 u32/px): lvl0 +0, lvl1 +1048576, lvl2 +1310720
// R19: k2 de-chunked: XCD permutation reverted (R18 evidence: k2 44->46us, XTb tile
// adjacency lost); gather now single-phase over full K=576 (LDS 32x292dw = 36.5KB,
// 4 blk/CU), all OFFM/MOD scalars preloaded (1 latency), all corner loads issued
// back-to-back (1 latency), ONE barrier (was 3), then 18 straight MFMA ks-steps.
// C stores float4. k1: stray mid-staging barrier removed.

struct P {
    const float *sou0, *sou1, *sou2;
    const float *ref0, *ref1, *ref2;
    const float *ob0, *ob1, *ob2;
    const float *mb0, *mb1, *mb2;
    float* out;
    float* ws;
};

union U {
    uint4 u4; int4 i4; short8 s8; f32x4 f4;
};

// ---------------- K0: fused weight repack (all levels) --------------------------------
__global__ __launch_bounds__(256) void repack_all(
    const float* __restrict__ ow0, const float* __restrict__ mw0, const float* __restrict__ rw0,
    const float* __restrict__ ow1, const float* __restrict__ mw1, const float* __restrict__ rw1,
    const float* __restrict__ ow2, const float* __restrict__ mw2, const float* __restrict__ rw2,
    float* __restrict__ dst) {
    const int lvl = blockIdx.y;
    const float* ow = lvl == 0 ? ow0 : (lvl == 1 ? ow1 : ow2);
    const float* mw = lvl == 0 ? mw0 : (lvl == 1 ? mw1 : mw2);
    const float* rw = lvl == 0 ? rw0 : (lvl == 1 ? rw1 : rw2);
    unsigned* d = (unsigned*)(dst + lvl * 62784);
    int i = blockIdx.x * 256 + threadIdx.x;
    if (i < 18432) {  // WB (dgemm): ((wvu*18+ks)*64+lane)*4+jw
        int jw = i & 3;
        int lane = (i >> 2) & 63;
        int t3 = i >> 8;
        int ks = t3 % 18, wvu = t3 / 18;
        int o = wvu * 16 + (lane & 15);
        int c0 = ks * 32 + (lane >> 4) * 8 + 2 * jw;
        int g0 = c0 / 144, r0 = c0 % 144;
        int c1 = c0 + 1;
        int g1 = c1 / 144, r1 = c1 % 144;
        float w0 = rw[o * 576 + (g0 * 16 + (r0 & 15)) * 9 + (r0 >> 4)];
        float w1 = rw[o * 576 + (g1 * 16 + (r1 & 15)) * 9 + (r1 >> 4)];
        d[i] = bf16rne(w0) | (bf16rne(w1) << 16);
    } else if (i < 23552) {  // WBO2: split-half offset B-frags (5120 u32)
        int o2 = i - 18432;
        int jw = o2 & 3;
        int lane = (o2 >> 2) & 63;
        int t2 = o2 >> 8;          // 0..19 = (h*5+ks)*2+nt
        int nt = t2 & 1;
        int hk = t2 >> 1;          // 0..9
        int ks = hk % 5, h = hk / 5;
        int n = nt * 16 + (lane & 15);
        int K = ks * 32 + (lane >> 4) * 8 + 2 * jw;
        int tap = K >> 4, ch = K & 15;
        bool ok = (n < 18) && (tap < 9);
        float w0 = ok ? ow[n * 288 + (h * 16 + ch) * 9 + tap] : 0.f;
        float w1 = ok ? ow[n * 288 + (h * 16 + ch + 1) * 9 + tap] : 0.f;
        d[36864 + o2] = bf16rne(w0) | (bf16rne(w1) << 16);
    } else if (i < 37376) {  // WBM (13824 u32) at 41984
        int o3 = i - 23552;
        int jw = o3 & 3;
        int lane = (o3 >> 2) & 63;
        int t3 = o3 >> 8;           // 0..53
        int nt = t3 % 3, tc = t3 / 3;
        int tap = tc >> 1, c = tc & 1;
        int n = nt * 16 + (lane & 15);
        int ic0 = c * 32 + (lane >> 4) * 8 + 2 * jw;
        float w0 = (n < 36) ? mw[n * 576 + ic0 * 9 + tap] : 0.f;
        float w1 = (n < 36) ? mw[n * 576 + (ic0 + 1) * 9 + tap] : 0.f;
        d[41984 + o3] = bf16rne(w0) | (bf16rne(w1) << 16);
    }
}

// ---------------- K1: fused mod+offset conv + XTb + MEAN (672 blocks) -----------------
__global__ __launch_bounds__(256) void k1_prep(P p) {
    __shared__ __align__(16) char smem[28512];  // 198 rows x 72 shorts
    const int t = blockIdx.x;
    float* ws = p.ws;
    const int tid = threadIdx.x;

    int lvl, j;
    if (t < 512) { lvl = 0; j = t; }
    else if (t < 640) { lvl = 1; j = t - 512; }
    else { lvl = 2; j = t - 640; }
    const int logW = 7 - lvl;
    const int W = 1 << logW, H = W, HW = H * W;
    const int nper = 256 >> (2 * lvl);
    const int qb = j % nper, b = j / nper;
    const int q0 = qb * 64;
    const int hlo = q0 >> logW;
    const int xlo = q0 & (W - 1);
    const int cols = (W >= 64) ? 66 : 34;
    const int rcTot = (W >= 64) ? 198 : 136;
    const float* sou = lvl == 0 ? p.sou0 : (lvl == 1 ? p.sou1 : p.sou2);
    const float* ref = lvl == 0 ? p.ref0 : (lvl == 1 ? p.ref1 : p.ref2);
    const float* base_s = sou + (size_t)b * 64 * HW;
    const float* base_r = ref + (size_t)b * 64 * HW;
    unsigned* ldsW = (unsigned*)smem;  // row stride 36 dw (72 shorts)
    const bool sact = tid < rcTot;
    const int srow = tid / cols, scol = tid - srow * cols;
    const int grow = hlo - 1 + srow, gcol = xlo - 1 + scol;
    const bool inb = sact && grow >= 0 && grow < H && gcol >= 0 && gcol < W;
    const size_t goff = inb ? ((size_t)grow * W + gcol) : 0;

    float v[32];
    // ---- stage sou: two 32-load bursts (all loads issued before first conversion) ----
#pragma unroll
    for (int hb = 0; hb < 2; ++hb) {
#pragma unroll
        for (int c8 = 0; c8 < 4; ++c8) {
            const float* p0 = base_s + (size_t)((hb * 4 + c8) * 8) * HW;
#pragma unroll
            for (int jj = 0; jj < 8; ++jj)
                v[c8 * 8 + jj] = inb ? p0[(size_t)jj * HW + goff] : 0.f;
        }
        if (sact) {
#pragma unroll
            for (int c8 = 0; c8 < 4; ++c8) {
                uint4 wv;
                wv.x = bf16rne(v[c8 * 8 + 0]) | (bf16rne(v[c8 * 8 + 1]) << 16);
                wv.y = bf16rne(v[c8 * 8 + 2]) | (bf16rne(v[c8 * 8 + 3]) << 16);
                wv.z = bf16rne(v[c8 * 8 + 4]) | (bf16rne(v[c8 * 8 + 5]) << 16);
                wv.w = bf16rne(v[c8 * 8 + 6]) | (bf16rne(v[c8 * 8 + 7]) << 16);
                *(uint4*)&ldsW[tid * 36 + (hb * 4 + c8) * 4] = wv;
            }
        }
    }
    __syncthreads();

    // ---- emit XTb for the central 64 px straight from the staged sou tile -----------
    unsigned* XTb = (unsigned*)(ws + 4919232) +
                    (lvl == 0 ? 0 : (lvl == 1 ? 1048576 : 1310720));
#pragma unroll
    for (int u = 0; u < 2; ++u) {
        const int idx = tid * 2 + u;       // 0..511
        const int px = idx >> 3, gh = idx & 7;
        const int g = gh >> 1, half = gh & 1;
        const int rc = ((px >> logW) + 1) * cols + (px & (W - 1)) + 1;
        uint4 vv = *(const uint4*)&ldsW[rc * 36 + g * 8 + half * 4];
        *(uint4*)(XTb + ((size_t)(b * 4 + g) * HW + q0 + px) * 8 + half * 4) = vv;
    }

    // ---- MFMA phase on sou tile: mod conv + offset half0 ----------------------------
    const int wvu = __builtin_amdgcn_readfirstlane(tid >> 6);
    const int lane = tid & 63, quad = lane >> 4, lo16 = lane & 15;
    const int qg = q0 + wvu * 16 + lo16;
    const int rowB = (qg >> logW) - hlo;
    const int colB = (qg & (W - 1)) - xlo;
    const unsigned short* ldsS = (const unsigned short*)smem;
    const unsigned* WREPu = (const unsigned*)(ws + 4730880 + lvl * 62784);
    const unsigned* WBO2 = WREPu + 36864;
    const unsigned* WBM = WREPu + 41984;

    f32x4 accM[3], accO[4][2];
#pragma unroll
    for (int nt = 0; nt < 3; ++nt) accM[nt] = (f32x4){0.f, 0.f, 0.f, 0.f};
#pragma unroll
    for (int g = 0; g < 4; ++g)
#pragma unroll
        for (int nt = 0; nt < 2; ++nt) accO[g][nt] = (f32x4){0.f, 0.f, 0.f, 0.f};

    // mod conv: 9 taps x 2 chunks x 3 ntiles
#pragma unroll
    for (int tap = 0; tap < 9; ++tap) {
        const int ky = tap / 3, kx = tap - ky * 3;
        const int rc = (rowB + ky) * cols + colB + kx;
#pragma unroll
        for (int c = 0; c < 2; ++c) {
            U au; au.s8 = *(const short8*)&ldsS[rc * 72 + c * 32 + quad * 8];
#pragma unroll
            for (int nt = 0; nt < 3; ++nt) {
                U bu;
                bu.u4 = *(const uint4*)(WBM + (((tap * 2 + c) * 3 + nt) * 64 + lane) * 4);
                accM[nt] = __builtin_amdgcn_mfma_f32_16x16x32_bf16(au.s8, bu.s8, accM[nt], 0, 0, 0);
            }
        }
    }
    // offset half0 (sou): B-frags hoisted above g loop (2 loads per ks, not 8)
#pragma unroll
    for (int ks = 0; ks < 5; ++ks) {
        const int Kbase = ks * 32 + quad * 8;
        const int tap = min(Kbase >> 4, 8);
        const int ky = tap / 3, kx = tap - ky * 3;
        const int rc = (rowB + ky) * cols + colB + kx;
        const int choff = Kbase & 15;  // 0 or 8
        U bu0, bu1;
        bu0.u4 = *(const uint4*)(WBO2 + ((ks * 2 + 0) * 64 + lane) * 4);
        bu1.u4 = *(const uint4*)(WBO2 + ((ks * 2 + 1) * 64 + lane) * 4);
#pragma unroll
        for (int g = 0; g < 4; ++g) {
            U au; au.s8 = *(const short8*)&ldsS[rc * 72 + g * 16 + choff];
            accO[g][0] = __builtin_amdgcn_mfma_f32_16x16x32_bf16(au.s8, bu0.s8, accO[g][0], 0, 0, 0);
            accO[g][1] = __builtin_amdgcn_mfma_f32_16x16x32_bf16(au.s8, bu1.s8, accO[g][1], 0, 0, 0);
        }
    }
    __syncthreads();

    // ---- re-stage ref (64 ch) in place, same two-burst pattern -----------------------
#pragma unroll
    for (int hb = 0; hb < 2; ++hb) {
#pragma unroll
        for (int c8 = 0; c8 < 4; ++c8) {
            const float* p0 = base_r + (size_t)((hb * 4 + c8) * 8) * HW;
#pragma unroll
            for (int jj = 0; jj < 8; ++jj)
                v[c8 * 8 + jj] = inb ? p0[(size_t)jj * HW + goff] : 0.f;
        }
        if (sact) {
#pragma unroll
            for (int c8 = 0; c8 < 4; ++c8) {
                uint4 wv;
                wv.x = bf16rne(v[c8 * 8 + 0]) | (bf16rne(v[c8 * 8 + 1]) << 16);
                wv.y = bf16rne(v[c8 * 8 + 2]) | (bf16rne(v[c8 * 8 + 3]) << 16);
                wv.z = bf16rne(v[c8 * 8 + 4]) | (bf16rne(v[c8 * 8 + 5]) << 16);
                wv.w = bf16rne(v[c8 * 8 + 6]) | (bf16rne(v[c8 * 8 + 7]) << 16);
                *(uint4*)&ldsW[tid * 36 + (hb * 4 + c8) * 4] = wv;
            }
        }
    }
    __syncthreads();

    // ---- offset half1 (ref) ----------------------------------------------------------
#pragma unroll
    for (int ks = 0; ks < 5; ++ks) {
        const int Kbase = ks * 32 + quad * 8;
        const int tap = min(Kbase >> 4, 8);
        const int ky = tap / 3, kx = tap - ky * 3;
        const int rc = (rowB + ky) * cols + colB + kx;
        const int choff = Kbase & 15;
        U bu0, bu1;
        bu0.u4 = *(const uint4*)(WBO2 + (((5 + ks) * 2 + 0) * 64 + lane) * 4);
        bu1.u4 = *(const uint4*)(WBO2 + (((5 + ks) * 2 + 1) * 64 + lane) * 4);
#pragma unroll
        for (int g = 0; g < 4; ++g) {
            U au; au.s8 = *(const short8*)&ldsS[rc * 72 + g * 16 + choff];
            accO[g][0] = __builtin_amdgcn_mfma_f32_16x16x32_bf16(au.s8, bu0.s8, accO[g][0], 0, 0, 0);
            accO[g][1] = __builtin_amdgcn_mfma_f32_16x16x32_bf16(au.s8, bu1.s8, accO[g][1], 0, 0, 0);
        }
    }

    // ---- epilogues ------------------------------------------------------------------
    {
        const float* bias = lvl == 0 ? p.mb0 : (lvl == 1 ? p.mb1 : p.mb2);
        float* MOD = ws + (lvl == 0 ? 3096576 : (lvl == 1 ? 4276224 : 4571136));
#pragma unroll
        for (int nt = 0; nt < 3; ++nt) {
            const int o = nt * 16 + lo16;
            if (o < 36) {
                const float bb = bias[o];
                float* op = MOD + (size_t)(b * 36 + o) * HW + q0 + wvu * 16 + quad * 4;
                *(float4*)op = make_float4(2.f * sigmoidf_(accM[nt][0] + bb),
                                           2.f * sigmoidf_(accM[nt][1] + bb),
                                           2.f * sigmoidf_(accM[nt][2] + bb),
                                           2.f * sigmoidf_(accM[nt][3] + bb));
            }
        }
    }
    {
        const float* bias = lvl == 0 ? p.ob0 : (lvl == 1 ? p.ob1 : p.ob2);
        float* OFFM = ws + (lvl == 0 ? 0 : (lvl == 1 ? 2359296 : 2949120));
        const float rng = 0.25f * (float)H;
        float macc[4] = {0.f, 0.f, 0.f, 0.f};  // per-lane partial of dy or dx sums
#pragma unroll
        for (int g = 0; g < 4; ++g)
#pragma unroll
            for (int nt = 0; nt < 2; ++nt) {
                const int o = nt * 16 + lo16;
                if (o < 18) {
                    const float bb = bias[o];
                    float ovv[4];
#pragma unroll
                    for (int rg = 0; rg < 4; ++rg)
                        ovv[rg] = rng * (2.f * sigmoidf_(accO[g][nt][rg] + bb) - 1.f);
                    float* op = OFFM + (size_t)(b * 72 + g * 18 + o) * HW + q0 + wvu * 16 + quad * 4;
                    *(float4*)op = make_float4(ovv[0], ovv[1], ovv[2], ovv[3]);
#pragma unroll
                    for (int rg = 0; rg < 4; ++rg) macc[rg] += ovv[rg];
                }
            }
        // o parity == lo16 parity: even lanes hold dy partials, odd lanes dx partials.
        const bool odd = (lo16 & 1) != 0;
        float my[4], mx[4];
#pragma unroll
        for (int rg = 0; rg < 4; ++rg) {
            my[rg] = odd ? 0.f : macc[rg];
            mx[rg] = odd ? macc[rg] : 0.f;
        }
#pragma unroll
        for (int m = 1; m < 16; m <<= 1) {
#pragma unroll
            for (int rg = 0; rg < 4; ++rg) {
                my[rg] += __shfl_xor(my[rg], m);
                mx[rg] += __shfl_xor(mx[rg], m);
            }
        }
        if (lo16 == 0) {
            float* MEAN = ws + (lvl == 0 ? 4644864 : (lvl == 1 ? 4710400 : 4726784));
            const int pxb = q0 + wvu * 16 + quad * 4;
            const float inv = 1.f / 36.f;
            *(float4*)(MEAN + (size_t)(b * 2) * HW + pxb) =
                make_float4(my[0] * inv, my[1] * inv, my[2] * inv, my[3] * inv);
            *(float4*)(MEAN + (size_t)(b * 2 + 1) * HW + pxb) =
                make_float4(mx[0] * inv, mx[1] * inv, mx[2] * inv, mx[3] * inv);
        }
    }
}

// ---------------- K2: FUSED gather+dgemm(1344, de-chunked) + upsample(3072) -----------
__global__ __launch_bounds__(256) void k2_fused(P p) {
    __shared__ __align__(16) unsigned lds[32 * 292];  // px-major, full K: 36.5 KB
    const int t = blockIdx.x;
    float* ws = p.ws;
    const int tid = threadIdx.x;
    if (t < 1344) {
        int lvl, j;
        if (t < 1024) { lvl = 0; j = t; }
        else if (t < 1280) { lvl = 1; j = t - 1024; }
        else { lvl = 2; j = t - 1280; }
        const int logW = 7 - lvl;
        const int W = 1 << logW, H = W, HW = H * W;
        const int nper = 512 >> (2 * lvl);
        const int qb = j % nper, b = j / nper;
        const int q0 = qb * 32;
        const float* OFFM = ws + (lvl == 0 ? 0 : (lvl == 1 ? 2359296 : 2949120));
        const float* MOD = ws + (lvl == 0 ? 3096576 : (lvl == 1 ? 4276224 : 4571136));
        const unsigned* XTb = (const unsigned*)(ws + 4919232) +
                              (lvl == 0 ? 0 : (lvl == 1 ? 1048576 : 1310720));
        const unsigned* WB = (const unsigned*)(ws + 4730880 + lvl * 62784);
        float* outp = p.out + (lvl == 0 ? 655360 : (lvl == 1 ? 131072 : 0));
        const int wvu = __builtin_amdgcn_readfirstlane(tid >> 6);
        const int lane = tid & 63, quad = lane >> 4, lo16 = lane & 15;

        // ---- preload all OFFM/MOD scalars (one exposed latency, coalesced in px) -----
        float dyv[5], dxv[5], mmv[5];
#pragma unroll
        for (int it = 0; it < 5; ++it) {
            const int tsk = it * 256 + tid;
            if (tsk < 1152) {
                const int gk = tsk >> 5, px = tsk & 31;
                const int g = gk / 9, k = gk - g * 9;
                const int q = q0 + px;
                dyv[it] = OFFM[(size_t)(b * 72 + g * 18 + 2 * k) * HW + q];
                dxv[it] = OFFM[(size_t)(b * 72 + g * 18 + 2 * k + 1) * HW + q];
                mmv[it] = MOD[(size_t)(b * 36 + g * 9 + k) * HW + q];
            }
        }
        // ---- gather all 36 gk x 32 px tasks (corner loads pipeline across tasks) -----
#pragma unroll
        for (int it = 0; it < 5; ++it) {
            const int tsk = it * 256 + tid;
            if (tsk < 1152) {
                const int gk = tsk >> 5, px = tsk & 31;
                const int g = gk / 9, k = gk - g * 9;
                const int q = q0 + px;
                const int h = q >> logW, xp = q & (W - 1);
                const int ky = k / 3, kx = k - ky * 3;
                float py = (float)(h - 1 + ky) + dyv[it];
                float pxx = (float)(xp - 1 + kx) + dxv[it];
                float y0f = floorf(py), x0f = floorf(pxx);
                float wy = py - y0f, wx = pxx - x0f;
                int y0 = (int)y0f, x0 = (int)x0f;
                const unsigned* xg = XTb + (size_t)(b * 4 + g) * HW * 8;
                float s[16];
#pragma unroll
                for (int cc = 0; cc < 16; ++cc) s[cc] = 0.f;
#pragma unroll
                for (int cor = 0; cor < 4; ++cor) {
                    int yy = y0 + (cor >> 1), xx = x0 + (cor & 1);
                    float cw = ((cor >> 1) ? wy : 1.f - wy) * ((cor & 1) ? wx : 1.f - wx);
                    cw = (yy >= 0 && yy < H && xx >= 0 && xx < W) ? cw * mmv[it] : 0.f;
                    int yc = min(max(yy, 0), H - 1), xc = min(max(xx, 0), W - 1);
                    const uint4* cp = (const uint4*)(xg + (size_t)((yc << logW) + xc) * 8);
                    unsigned cbuf[8];
                    *(uint4*)&cbuf[0] = cp[0];
                    *(uint4*)&cbuf[4] = cp[1];
#pragma unroll
                    for (int pr = 0; pr < 8; ++pr) {
                        float lo = __uint_as_float(cbuf[pr] << 16);
                        float hi = __uint_as_float(cbuf[pr] & 0xFFFF0000u);
                        s[2 * pr] = fmaf(cw, lo, s[2 * pr]);
                        s[2 * pr + 1] = fmaf(cw, hi, s[2 * pr + 1]);
                    }
                }
                // px-major store: K-cols gk*8..gk*8+7 as two b128 writes
                unsigned* dp = &lds[px * 292 + gk * 8];
                uint4 w0, w1;
                w0.x = bf16rne(s[0]) | (bf16rne(s[1]) << 16);
                w0.y = bf16rne(s[2]) | (bf16rne(s[3]) << 16);
                w0.z = bf16rne(s[4]) | (bf16rne(s[5]) << 16);
                w0.w = bf16rne(s[6]) | (bf16rne(s[7]) << 16);
                w1.x = bf16rne(s[8]) | (bf16rne(s[9]) << 16);
                w1.y = bf16rne(s[10]) | (bf16rne(s[11]) << 16);
                w1.z = bf16rne(s[12]) | (bf16rne(s[13]) << 16);
                w1.w = bf16rne(s[14]) | (bf16rne(s[15]) << 16);
                *(uint4*)dp = w0;
                *(uint4*)(dp + 4) = w1;
            }
        }
        __syncthreads();  // the ONE barrier

        // ---- 18 ks-steps of MFMA straight through ------------------------------------
        f32x4 acc[2];
        acc[0] = (f32x4){0.f, 0.f, 0.f, 0.f};
        acc[1] = (f32x4){0.f, 0.f, 0.f, 0.f};
#pragma unroll
        for (int ks = 0; ks < 18; ++ks) {
            U bu;
            bu.u4 = *(const uint4*)(WB + (((wvu * 18 + ks) * 64 + lane) << 2));
#pragma unroll
            for (int mt = 0; mt < 2; ++mt) {
                U au;
                au.u4 = *(const uint4*)&lds[(mt * 16 + lo16) * 292 + ks * 16 + quad * 4];
                acc[mt] = __builtin_amdgcn_mfma_f32_16x16x32_bf16(au.s8, bu.s8, acc[mt], 0, 0, 0);
            }
        }
        float* op = outp + (size_t)(b * 64 + wvu * 16 + lo16) * HW + q0;
#pragma unroll
        for (int mt = 0; mt < 2; ++mt)
            *(f32x4*)(op + mt * 16 + quad * 4) = acc[mt];
    } else {
        // ---- upsample (formerly K3): MEAN written by k1, independent of gemm blocks --
        int flat = ((t - 1344) * 256 + tid) * 4;
        int lvl = flat >> 20;
        int r = flat & 1048575;
        int b = r >> 19, c = (r >> 18) & 1;
        int pix = r & 262143;
        int yo = pix >> 9, xo = pix & 511;
        const int H = 128 >> lvl, W = H;
        const float* MEAN = ws + (lvl == 0 ? 4644864 : (lvl == 1 ? 4710400 : 4726784));
        const float* m = MEAN + (size_t)(b * 2 + c) * H * W;
        float* o = p.out + (lvl == 0 ? 4849664 : (lvl == 1 ? 3801088 : 2752512)) +
                   ((size_t)(b * 2 + c) * 512 + yo) * 512 + xo;
        const float fs = (float)(4 << lvl);
        const float sc = (float)(H - 1) * (1.f / 511.f);
        float sy = yo * sc;
        int y0 = min((int)sy, H - 2);
        float wy = sy - (float)y0;
        float rr[4];
#pragma unroll
        for (int u = 0; u < 4; ++u) {
            float sx = (float)(xo + u) * sc;
            int x0 = min((int)sx, W - 2);
            float wx = sx - (float)x0;
            float v00 = m[y0 * W + x0], v01 = m[y0 * W + x0 + 1];
            float v10 = m[(y0 + 1) * W + x0], v11 = m[(y0 + 1) * W + x0 + 1];
            float r0 = v00 * (1.f - wy) + v10 * wy;
            float r1 = v01 * (1.f - wy) + v11 * wy;
            rr[u] = (r0 * (1.f - wx) + r1 * wx) * fs;
        }
        *(float4*)o = make_float4(rr[0], rr[1], rr[2], rr[3]);
    }
}

extern "C" void kernel_launch(void* const* d_in, const int* in_sizes, int n_in,
                              void* d_out, int out_size, void* d_ws, size_t ws_size,
                              hipStream_t stream) {
    const float* fin[21];
    for (int i = 0; i < 21; ++i) fin[i] = (const float*)d_in[i];
    P p;
    if (in_sizes[1] == in_sizes[0]) {  // dict order sou1,ref1,sou2,ref2,sou3,ref3
        p.sou0 = fin[0]; p.ref0 = fin[1];
        p.sou1 = fin[2]; p.ref1 = fin[3];
        p.sou2 = fin[4]; p.ref2 = fin[5];
    } else {  // arg order
        p.sou0 = fin[0]; p.sou1 = fin[1]; p.sou2 = fin[2];
        p.ref0 = fin[3]; p.ref1 = fin[4]; p.ref2 = fin[5];
    }
    p.ob0 = fin[7]; p.mb0 = fin[9];
    p.ob1 = fin[12]; p.mb1 = fin[14];
    p.ob2 = fin[17]; p.mb2 = fin[19];
    p.out = (float*)d_out;
    p.ws = (float*)d_ws;

    repack_all<<<dim3(146, 3), 256, 0, stream>>>(
        fin[6], fin[8], fin[10], fin[11], fin[13], fin[15], fin[16], fin[18], fin[20],
        p.ws + 4730880);
    k1_prep<<<dim3(672), 256, 0, stream>>>(p);
    k2_fused<<<dim3(4416), 256, 0, stream>>>(p);
}

// Round 5
// 168.133 us; speedup vs baseline: 1.0512x; 1.0113x over previous
//
#include <hip/hip_runtime.h>

typedef __attribute__((ext_vector_type(8))) short short8;
typedef __attribute__((ext_vector_type(4))) float f32x4;

__device__ __forceinline__ float sigmoidf_(float x) { return 1.f / (1.f + __expf(-x)); }
__device__ __forceinline__ unsigned bf16rne(float x) {
    unsigned b = __float_as_uint(x);
    return (b + 0x7FFFu + ((b >> 16) & 1u)) >> 16;
}

// ws layout (float words):
//   OFFM:  lvl0 @0 (2359296), lvl1 @2359296 (589824), lvl2 @2949120 (147456)
//   MOD:   lvl0 @3096576 (1179648), lvl1 @4276224 (294912), lvl2 @4571136 (73728)
//   MEAN:  lvl0 @4644864 (65536), lvl1 @4710400 (16384), lvl2 @4726784 (4096)
//   WREP:  @4730880, 3*62784 floats; per lvl as u32:
//          [0..18432)     WB   dgemm B-frags
//          [36864..41984) WBO2 offset-conv B-frags, split-half K
//          [41984..55808) WBM  mod-conv B-frags
//   XTb:   @4919232 as u32 (bf16 pairs, 8 u32/px): lvl0 +0, lvl1 +1048576, lvl2 +1310720
// R20: k1 de-serialized. R19 evidence: VGPR fell 88->60 (compiler targeted 8 waves/EU),
// serializing the ~128 staging loads into tiny batches -> 47us of exposed latency at
// grid-limited 2.6 blocks/CU where the 60-VGPR occupancy target buys nothing.
// Fix: __launch_bounds__(256,2) + single vs[64] sou burst + vr[64] ref prefetch issued
// before the MFMA phases (register-level T14; LDS write stays after the barrier, LDS
// stays 28.5KB, barrier count unchanged -> bit-identical output).

struct P {
    const float *sou0, *sou1, *sou2;
    const float *ref0, *ref1, *ref2;
    const float *ob0, *ob1, *ob2;
    const float *mb0, *mb1, *mb2;
    float* out;
    float* ws;
};

union U {
    uint4 u4; int4 i4; short8 s8; f32x4 f4;
};

// ---------------- K0: fused weight repack (all levels) --------------------------------
__global__ __launch_bounds__(256) void repack_all(
    const float* __restrict__ ow0, const float* __restrict__ mw0, const float* __restrict__ rw0,
    const float* __restrict__ ow1, const float* __restrict__ mw1, const float* __restrict__ rw1,
    const float* __restrict__ ow2, const float* __restrict__ mw2, const float* __restrict__ rw2,
    float* __restrict__ dst) {
    const int lvl = blockIdx.y;
    const float* ow = lvl == 0 ? ow0 : (lvl == 1 ? ow1 : ow2);
    const float* mw = lvl == 0 ? mw0 : (lvl == 1 ? mw1 : mw2);
    const float* rw = lvl == 0 ? rw0 : (lvl == 1 ? rw1 : rw2);
    unsigned* d = (unsigned*)(dst + lvl * 62784);
    int i = blockIdx.x * 256 + threadIdx.x;
    if (i < 18432) {  // WB (dgemm): ((wvu*18+ks)*64+lane)*4+jw
        int jw = i & 3;
        int lane = (i >> 2) & 63;
        int t3 = i >> 8;
        int ks = t3 % 18, wvu = t3 / 18;
        int o = wvu * 16 + (lane & 15);
        int c0 = ks * 32 + (lane >> 4) * 8 + 2 * jw;
        int g0 = c0 / 144, r0 = c0 % 144;
        int c1 = c0 + 1;
        int g1 = c1 / 144, r1 = c1 % 144;
        float w0 = rw[o * 576 + (g0 * 16 + (r0 & 15)) * 9 + (r0 >> 4)];
        float w1 = rw[o * 576 + (g1 * 16 + (r1 & 15)) * 9 + (r1 >> 4)];
        d[i] = bf16rne(w0) | (bf16rne(w1) << 16);
    } else if (i < 23552) {  // WBO2: split-half offset B-frags (5120 u32)
        int o2 = i - 18432;
        int jw = o2 & 3;
        int lane = (o2 >> 2) & 63;
        int t2 = o2 >> 8;          // 0..19 = (h*5+ks)*2+nt
        int nt = t2 & 1;
        int hk = t2 >> 1;          // 0..9
        int ks = hk % 5, h = hk / 5;
        int n = nt * 16 + (lane & 15);
        int K = ks * 32 + (lane >> 4) * 8 + 2 * jw;
        int tap = K >> 4, ch = K & 15;
        bool ok = (n < 18) && (tap < 9);
        float w0 = ok ? ow[n * 288 + (h * 16 + ch) * 9 + tap] : 0.f;
        float w1 = ok ? ow[n * 288 + (h * 16 + ch + 1) * 9 + tap] : 0.f;
        d[36864 + o2] = bf16rne(w0) | (bf16rne(w1) << 16);
    } else if (i < 37376) {  // WBM (13824 u32) at 41984
        int o3 = i - 23552;
        int jw = o3 & 3;
        int lane = (o3 >> 2) & 63;
        int t3 = o3 >> 8;           // 0..53
        int nt = t3 % 3, tc = t3 / 3;
        int tap = tc >> 1, c = tc & 1;
        int n = nt * 16 + (lane & 15);
        int ic0 = c * 32 + (lane >> 4) * 8 + 2 * jw;
        float w0 = (n < 36) ? mw[n * 576 + ic0 * 9 + tap] : 0.f;
        float w1 = (n < 36) ? mw[n * 576 + (ic0 + 1) * 9 + tap] : 0.f;
        d[41984 + o3] = bf16rne(w0) | (bf16rne(w1) << 16);
    }
}

// ---------------- K1: fused mod+offset conv + XTb + MEAN (672 blocks) -----------------
__global__ __launch_bounds__(256, 2) void k1_prep(P p) {
    __shared__ __align__(16) char smem[28512];  // 198 rows x 72 shorts
    const int t = blockIdx.x;
    float* ws = p.ws;
    const int tid = threadIdx.x;

    int lvl, j;
    if (t < 512) { lvl = 0; j = t; }
    else if (t < 640) { lvl = 1; j = t - 512; }
    else { lvl = 2; j = t - 640; }
    const int logW = 7 - lvl;
    const int W = 1 << logW, H = W, HW = H * W;
    const int nper = 256 >> (2 * lvl);
    const int qb = j % nper, b = j / nper;
    const int q0 = qb * 64;
    const int hlo = q0 >> logW;
    const int xlo = q0 & (W - 1);
    const int cols = (W >= 64) ? 66 : 34;
    const int rcTot = (W >= 64) ? 198 : 136;
    const float* sou = lvl == 0 ? p.sou0 : (lvl == 1 ? p.sou1 : p.sou2);
    const float* ref = lvl == 0 ? p.ref0 : (lvl == 1 ? p.ref1 : p.ref2);
    const float* base_s = sou + (size_t)b * 64 * HW;
    const float* base_r = ref + (size_t)b * 64 * HW;
    unsigned* ldsW = (unsigned*)smem;  // row stride 36 dw (72 shorts)
    const bool sact = tid < rcTot;
    const int srow = tid / cols, scol = tid - srow * cols;
    const int grow = hlo - 1 + srow, gcol = xlo - 1 + scol;
    const bool inb = sact && grow >= 0 && grow < H && gcol >= 0 && gcol < W;
    const size_t goff = inb ? ((size_t)grow * W + gcol) : 0;

    // ---- stage sou: ONE 64-load burst, then convert+write ---------------------------
    float vs[64];
#pragma unroll
    for (int c8 = 0; c8 < 8; ++c8) {
        const float* p0 = base_s + (size_t)(c8 * 8) * HW;
#pragma unroll
        for (int jj = 0; jj < 8; ++jj)
            vs[c8 * 8 + jj] = inb ? p0[(size_t)jj * HW + goff] : 0.f;
    }
    if (sact) {
#pragma unroll
        for (int c8 = 0; c8 < 8; ++c8) {
            uint4 wv;
            wv.x = bf16rne(vs[c8 * 8 + 0]) | (bf16rne(vs[c8 * 8 + 1]) << 16);
            wv.y = bf16rne(vs[c8 * 8 + 2]) | (bf16rne(vs[c8 * 8 + 3]) << 16);
            wv.z = bf16rne(vs[c8 * 8 + 4]) | (bf16rne(vs[c8 * 8 + 5]) << 16);
            wv.w = bf16rne(vs[c8 * 8 + 6]) | (bf16rne(vs[c8 * 8 + 7]) << 16);
            *(uint4*)&ldsW[tid * 36 + c8 * 4] = wv;
        }
    }
    __syncthreads();

    // ---- emit XTb for the central 64 px straight from the staged sou tile -----------
    unsigned* XTb = (unsigned*)(ws + 4919232) +
                    (lvl == 0 ? 0 : (lvl == 1 ? 1048576 : 1310720));
#pragma unroll
    for (int u = 0; u < 2; ++u) {
        const int idx = tid * 2 + u;       // 0..511
        const int px = idx >> 3, gh = idx & 7;
        const int g = gh >> 1, half = gh & 1;
        const int rc = ((px >> logW) + 1) * cols + (px & (W - 1)) + 1;
        uint4 vv = *(const uint4*)&ldsW[rc * 36 + g * 8 + half * 4];
        *(uint4*)(XTb + ((size_t)(b * 4 + g) * HW + q0 + px) * 8 + half * 4) = vv;
    }

    // ---- prefetch ref (64 ch) into registers; loads fly under the MFMA phases -------
    float vr[64];
#pragma unroll
    for (int c8 = 0; c8 < 8; ++c8) {
        const float* p0 = base_r + (size_t)(c8 * 8) * HW;
#pragma unroll
        for (int jj = 0; jj < 8; ++jj)
            vr[c8 * 8 + jj] = inb ? p0[(size_t)jj * HW + goff] : 0.f;
    }

    // ---- MFMA phase on sou tile: mod conv + offset half0 ----------------------------
    const int wvu = __builtin_amdgcn_readfirstlane(tid >> 6);
    const int lane = tid & 63, quad = lane >> 4, lo16 = lane & 15;
    const int qg = q0 + wvu * 16 + lo16;
    const int rowB = (qg >> logW) - hlo;
    const int colB = (qg & (W - 1)) - xlo;
    const unsigned short* ldsS = (const unsigned short*)smem;
    const unsigned* WREPu = (const unsigned*)(ws + 4730880 + lvl * 62784);
    const unsigned* WBO2 = WREPu + 36864;
    const unsigned* WBM = WREPu + 41984;

    f32x4 accM[3], accO[4][2];
#pragma unroll
    for (int nt = 0; nt < 3; ++nt) accM[nt] = (f32x4){0.f, 0.f, 0.f, 0.f};
#pragma unroll
    for (int g = 0; g < 4; ++g)
#pragma unroll
        for (int nt = 0; nt < 2; ++nt) accO[g][nt] = (f32x4){0.f, 0.f, 0.f, 0.f};

    // mod conv: 9 taps x 2 chunks x 3 ntiles
#pragma unroll
    for (int tap = 0; tap < 9; ++tap) {
        const int ky = tap / 3, kx = tap - ky * 3;
        const int rc = (rowB + ky) * cols + colB + kx;
#pragma unroll
        for (int c = 0; c < 2; ++c) {
            U au; au.s8 = *(const short8*)&ldsS[rc * 72 + c * 32 + quad * 8];
#pragma unroll
            for (int nt = 0; nt < 3; ++nt) {
                U bu;
                bu.u4 = *(const uint4*)(WBM + (((tap * 2 + c) * 3 + nt) * 64 + lane) * 4);
                accM[nt] = __builtin_amdgcn_mfma_f32_16x16x32_bf16(au.s8, bu.s8, accM[nt], 0, 0, 0);
            }
        }
    }
    // offset half0 (sou): B-frags hoisted above g loop (2 loads per ks, not 8)
#pragma unroll
    for (int ks = 0; ks < 5; ++ks) {
        const int Kbase = ks * 32 + quad * 8;
        const int tap = min(Kbase >> 4, 8);
        const int ky = tap / 3, kx = tap - ky * 3;
        const int rc = (rowB + ky) * cols + colB + kx;
        const int choff = Kbase & 15;  // 0 or 8
        U bu0, bu1;
        bu0.u4 = *(const uint4*)(WBO2 + ((ks * 2 + 0) * 64 + lane) * 4);
        bu1.u4 = *(const uint4*)(WBO2 + ((ks * 2 + 1) * 64 + lane) * 4);
#pragma unroll
        for (int g = 0; g < 4; ++g) {
            U au; au.s8 = *(const short8*)&ldsS[rc * 72 + g * 16 + choff];
            accO[g][0] = __builtin_amdgcn_mfma_f32_16x16x32_bf16(au.s8, bu0.s8, accO[g][0], 0, 0, 0);
            accO[g][1] = __builtin_amdgcn_mfma_f32_16x16x32_bf16(au.s8, bu1.s8, accO[g][1], 0, 0, 0);
        }
    }
    __syncthreads();

    // ---- write prefetched ref tile to LDS (in place) ---------------------------------
    if (sact) {
#pragma unroll
        for (int c8 = 0; c8 < 8; ++c8) {
            uint4 wv;
            wv.x = bf16rne(vr[c8 * 8 + 0]) | (bf16rne(vr[c8 * 8 + 1]) << 16);
            wv.y = bf16rne(vr[c8 * 8 + 2]) | (bf16rne(vr[c8 * 8 + 3]) << 16);
            wv.z = bf16rne(vr[c8 * 8 + 4]) | (bf16rne(vr[c8 * 8 + 5]) << 16);
            wv.w = bf16rne(vr[c8 * 8 + 6]) | (bf16rne(vr[c8 * 8 + 7]) << 16);
            *(uint4*)&ldsW[tid * 36 + c8 * 4] = wv;
        }
    }
    __syncthreads();

    // ---- offset half1 (ref) ----------------------------------------------------------
#pragma unroll
    for (int ks = 0; ks < 5; ++ks) {
        const int Kbase = ks * 32 + quad * 8;
        const int tap = min(Kbase >> 4, 8);
        const int ky = tap / 3, kx = tap - ky * 3;
        const int rc = (rowB + ky) * cols + colB + kx;
        const int choff = Kbase & 15;
        U bu0, bu1;
        bu0.u4 = *(const uint4*)(WBO2 + (((5 + ks) * 2 + 0) * 64 + lane) * 4);
        bu1.u4 = *(const uint4*)(WBO2 + (((5 + ks) * 2 + 1) * 64 + lane) * 4);
#pragma unroll
        for (int g = 0; g < 4; ++g) {
            U au; au.s8 = *(const short8*)&ldsS[rc * 72 + g * 16 + choff];
            accO[g][0] = __builtin_amdgcn_mfma_f32_16x16x32_bf16(au.s8, bu0.s8, accO[g][0], 0, 0, 0);
            accO[g][1] = __builtin_amdgcn_mfma_f32_16x16x32_bf16(au.s8, bu1.s8, accO[g][1], 0, 0, 0);
        }
    }

    // ---- epilogues ------------------------------------------------------------------
    {
        const float* bias = lvl == 0 ? p.mb0 : (lvl == 1 ? p.mb1 : p.mb2);
        float* MOD = ws + (lvl == 0 ? 3096576 : (lvl == 1 ? 4276224 : 4571136));
#pragma unroll
        for (int nt = 0; nt < 3; ++nt) {
            const int o = nt * 16 + lo16;
            if (o < 36) {
                const float bb = bias[o];
                float* op = MOD + (size_t)(b * 36 + o) * HW + q0 + wvu * 16 + quad * 4;
                *(float4*)op = make_float4(2.f * sigmoidf_(accM[nt][0] + bb),
                                           2.f * sigmoidf_(accM[nt][1] + bb),
                                           2.f * sigmoidf_(accM[nt][2] + bb),
                                           2.f * sigmoidf_(accM[nt][3] + bb));
            }
        }
    }
    {
        const float* bias = lvl == 0 ? p.ob0 : (lvl == 1 ? p.ob1 : p.ob2);
        float* OFFM = ws + (lvl == 0 ? 0 : (lvl == 1 ? 2359296 : 2949120));
        const float rng = 0.25f * (float)H;
        float macc[4] = {0.f, 0.f, 0.f, 0.f};  // per-lane partial of dy or dx sums
#pragma unroll
        for (int g = 0; g < 4; ++g)
#pragma unroll
            for (int nt = 0; nt < 2; ++nt) {
                const int o = nt * 16 + lo16;
                if (o < 18) {
                    const float bb = bias[o];
                    float ovv[4];
#pragma unroll
                    for (int rg = 0; rg < 4; ++rg)
                        ovv[rg] = rng * (2.f * sigmoidf_(accO[g][nt][rg] + bb) - 1.f);
                    float* op = OFFM + (size_t)(b * 72 + g * 18 + o) * HW + q0 + wvu * 16 + quad * 4;
                    *(float4*)op = make_float4(ovv[0], ovv[1], ovv[2], ovv[3]);
#pragma unroll
                    for (int rg = 0; rg < 4; ++rg) macc[rg] += ovv[rg];
                }
            }
        // o parity == lo16 parity: even lanes hold dy partials, odd lanes dx partials.
        const bool odd = (lo16 & 1) != 0;
        float my[4], mx[4];
#pragma unroll
        for (int rg = 0; rg < 4; ++rg) {
            my[rg] = odd ? 0.f : macc[rg];
            mx[rg] = odd ? macc[rg] : 0.f;
        }
#pragma unroll
        for (int m = 1; m < 16; m <<= 1) {
#pragma unroll
            for (int rg = 0; rg < 4; ++rg) {
                my[rg] += __shfl_xor(my[rg], m);
                mx[rg] += __shfl_xor(mx[rg], m);
            }
        }
        if (lo16 == 0) {
            float* MEAN = ws + (lvl == 0 ? 4644864 : (lvl == 1 ? 4710400 : 4726784));
            const int pxb = q0 + wvu * 16 + quad * 4;
            const float inv = 1.f / 36.f;
            *(float4*)(MEAN + (size_t)(b * 2) * HW + pxb) =
                make_float4(my[0] * inv, my[1] * inv, my[2] * inv, my[3] * inv);
            *(float4*)(MEAN + (size_t)(b * 2 + 1) * HW + pxb) =
                make_float4(mx[0] * inv, mx[1] * inv, mx[2] * inv, mx[3] * inv);
        }
    }
}

// ---------------- K2: FUSED gather+dgemm(1344, de-chunked) + upsample(3072) -----------
__global__ __launch_bounds__(256) void k2_fused(P p) {
    __shared__ __align__(16) unsigned lds[32 * 292];  // px-major, full K: 36.5 KB
    const int t = blockIdx.x;
    float* ws = p.ws;
    const int tid = threadIdx.x;
    if (t < 1344) {
        int lvl, j;
        if (t < 1024) { lvl = 0; j = t; }
        else if (t < 1280) { lvl = 1; j = t - 1024; }
        else { lvl = 2; j = t - 1280; }
        const int logW = 7 - lvl;
        const int W = 1 << logW, H = W, HW = H * W;
        const int nper = 512 >> (2 * lvl);
        const int qb = j % nper, b = j / nper;
        const int q0 = qb * 32;
        const float* OFFM = ws + (lvl == 0 ? 0 : (lvl == 1 ? 2359296 : 2949120));
        const float* MOD = ws + (lvl == 0 ? 3096576 : (lvl == 1 ? 4276224 : 4571136));
        const unsigned* XTb = (const unsigned*)(ws + 4919232) +
                              (lvl == 0 ? 0 : (lvl == 1 ? 1048576 : 1310720));
        const unsigned* WB = (const unsigned*)(ws + 4730880 + lvl * 62784);
        float* outp = p.out + (lvl == 0 ? 655360 : (lvl == 1 ? 131072 : 0));
        const int wvu = __builtin_amdgcn_readfirstlane(tid >> 6);
        const int lane = tid & 63, quad = lane >> 4, lo16 = lane & 15;

        // ---- preload all OFFM/MOD scalars (one exposed latency, coalesced in px) -----
        float dyv[5], dxv[5], mmv[5];
#pragma unroll
        for (int it = 0; it < 5; ++it) {
            const int tsk = it * 256 + tid;
            if (tsk < 1152) {
                const int gk = tsk >> 5, px = tsk & 31;
                const int g = gk / 9, k = gk - g * 9;
                const int q = q0 + px;
                dyv[it] = OFFM[(size_t)(b * 72 + g * 18 + 2 * k) * HW + q];
                dxv[it] = OFFM[(size_t)(b * 72 + g * 18 + 2 * k + 1) * HW + q];
                mmv[it] = MOD[(size_t)(b * 36 + g * 9 + k) * HW + q];
            }
        }
        // ---- gather all 36 gk x 32 px tasks (corner loads pipeline across tasks) -----
#pragma unroll
        for (int it = 0; it < 5; ++it) {
            const int tsk = it * 256 + tid;
            if (tsk < 1152) {
                const int gk = tsk >> 5, px = tsk & 31;
                const int g = gk / 9, k = gk - g * 9;
                const int q = q0 + px;
                const int h = q >> logW, xp = q & (W - 1);
                const int ky = k / 3, kx = k - ky * 3;
                float py = (float)(h - 1 + ky) + dyv[it];
                float pxx = (float)(xp - 1 + kx) + dxv[it];
                float y0f = floorf(py), x0f = floorf(pxx);
                float wy = py - y0f, wx = pxx - x0f;
                int y0 = (int)y0f, x0 = (int)x0f;
                const unsigned* xg = XTb + (size_t)(b * 4 + g) * HW * 8;
                float s[16];
#pragma unroll
                for (int cc = 0; cc < 16; ++cc) s[cc] = 0.f;
#pragma unroll
                for (int cor = 0; cor < 4; ++cor) {
                    int yy = y0 + (cor >> 1), xx = x0 + (cor & 1);
                    float cw = ((cor >> 1) ? wy : 1.f - wy) * ((cor & 1) ? wx : 1.f - wx);
                    cw = (yy >= 0 && yy < H && xx >= 0 && xx < W) ? cw * mmv[it] : 0.f;
                    int yc = min(max(yy, 0), H - 1), xc = min(max(xx, 0), W - 1);
                    const uint4* cp = (const uint4*)(xg + (size_t)((yc << logW) + xc) * 8);
                    unsigned cbuf[8];
                    *(uint4*)&cbuf[0] = cp[0];
                    *(uint4*)&cbuf[4] = cp[1];
#pragma unroll
                    for (int pr = 0; pr < 8; ++pr) {
                        float lo = __uint_as_float(cbuf[pr] << 16);
                        float hi = __uint_as_float(cbuf[pr] & 0xFFFF0000u);
                        s[2 * pr] = fmaf(cw, lo, s[2 * pr]);
                        s[2 * pr + 1] = fmaf(cw, hi, s[2 * pr + 1]);
                    }
                }
                // px-major store: K-cols gk*8..gk*8+7 as two b128 writes
                unsigned* dp = &lds[px * 292 + gk * 8];
                uint4 w0, w1;
                w0.x = bf16rne(s[0]) | (bf16rne(s[1]) << 16);
                w0.y = bf16rne(s[2]) | (bf16rne(s[3]) << 16);
                w0.z = bf16rne(s[4]) | (bf16rne(s[5]) << 16);
                w0.w = bf16rne(s[6]) | (bf16rne(s[7]) << 16);
                w1.x = bf16rne(s[8]) | (bf16rne(s[9]) << 16);
                w1.y = bf16rne(s[10]) | (bf16rne(s[11]) << 16);
                w1.z = bf16rne(s[12]) | (bf16rne(s[13]) << 16);
                w1.w = bf16rne(s[14]) | (bf16rne(s[15]) << 16);
                *(uint4*)dp = w0;
                *(uint4*)(dp + 4) = w1;
            }
        }
        __syncthreads();  // the ONE barrier

        // ---- 18 ks-steps of MFMA straight through ------------------------------------
        f32x4 acc[2];
        acc[0] = (f32x4){0.f, 0.f, 0.f, 0.f};
        acc[1] = (f32x4){0.f, 0.f, 0.f, 0.f};
#pragma unroll
        for (int ks = 0; ks < 18; ++ks) {
            U bu;
            bu.u4 = *(const uint4*)(WB + (((wvu * 18 + ks) * 64 + lane) << 2));
#pragma unroll
            for (int mt = 0; mt < 2; ++mt) {
                U au;
                au.u4 = *(const uint4*)&lds[(mt * 16 + lo16) * 292 + ks * 16 + quad * 4];
                acc[mt] = __builtin_amdgcn_mfma_f32_16x16x32_bf16(au.s8, bu.s8, acc[mt], 0, 0, 0);
            }
        }
        float* op = outp + (size_t)(b * 64 + wvu * 16 + lo16) * HW + q0;
#pragma unroll
        for (int mt = 0; mt < 2; ++mt)
            *(f32x4*)(op + mt * 16 + quad * 4) = acc[mt];
    } else {
        // ---- upsample (formerly K3): MEAN written by k1, independent of gemm blocks --
        int flat = ((t - 1344) * 256 + tid) * 4;
        int lvl = flat >> 20;
        int r = flat & 1048575;
        int b = r >> 19, c = (r >> 18) & 1;
        int pix = r & 262143;
        int yo = pix >> 9, xo = pix & 511;
        const int H = 128 >> lvl, W = H;
        const float* MEAN = ws + (lvl == 0 ? 4644864 : (lvl == 1 ? 4710400 : 4726784));
        const float* m = MEAN + (size_t)(b * 2 + c) * H * W;
        float* o = p.out + (lvl == 0 ? 4849664 : (lvl == 1 ? 3801088 : 2752512)) +
                   ((size_t)(b * 2 + c) * 512 + yo) * 512 + xo;
        const float fs = (float)(4 << lvl);
        const float sc = (float)(H - 1) * (1.f / 511.f);
        float sy = yo * sc;
        int y0 = min((int)sy, H - 2);
        float wy = sy - (float)y0;
        float rr[4];
#pragma unroll
        for (int u = 0; u < 4; ++u) {
            float sx = (float)(xo + u) * sc;
            int x0 = min((int)sx, W - 2);
            float wx = sx - (float)x0;
            float v00 = m[y0 * W + x0], v01 = m[y0 * W + x0 + 1];
            float v10 = m[(y0 + 1) * W + x0], v11 = m[(y0 + 1) * W + x0 + 1];
            float r0 = v00 * (1.f - wy) + v10 * wy;
            float r1 = v01 * (1.f - wy) + v11 * wy;
            rr[u] = (r0 * (1.f - wx) + r1 * wx) * fs;
        }
        *(float4*)o = make_float4(rr[0], rr[1], rr[2], rr[3]);
    }
}

extern "C" void kernel_launch(void* const* d_in, const int* in_sizes, int n_in,
                              void* d_out, int out_size, void* d_ws, size_t ws_size,
                              hipStream_t stream) {
    const float* fin[21];
    for (int i = 0; i < 21; ++i) fin[i] = (const float*)d_in[i];
    P p;
    if (in_sizes[1] == in_sizes[0]) {  // dict order sou1,ref1,sou2,ref2,sou3,ref3
        p.sou0 = fin[0]; p.ref0 = fin[1];
        p.sou1 = fin[2]; p.ref1 = fin[3];
        p.sou2 = fin[4]; p.ref2 = fin[5];
    } else {  // arg order
        p.sou0 = fin[0]; p.sou1 = fin[1]; p.sou2 = fin[2];
        p.ref0 = fin[3]; p.ref1 = fin[4]; p.ref2 = fin[5];
    }
    p.ob0 = fin[7]; p.mb0 = fin[9];
    p.ob1 = fin[12]; p.mb1 = fin[14];
    p.ob2 = fin[17]; p.mb2 = fin[19];
    p.out = (float*)d_out;
    p.ws = (float*)d_ws;

    repack_all<<<dim3(146, 3), 256, 0, stream>>>(
        fin[6], fin[8], fin[10], fin[11], fin[13], fin[15], fin[16], fin[18], fin[20],
        p.ws + 4730880);
    k1_prep<<<dim3(672), 256, 0, stream>>>(p);
    k2_fused<<<dim3(4416), 256, 0, stream>>>(p);
}